// Round 12
// baseline (4357.185 us; speedup 1.0000x reference)
//
#include <hip/hip_runtime.h>
#include <hip/hip_bf16.h>

#define B_ 64
#define S_ 512
#define D_ 256
#define H_ 512

typedef __attribute__((ext_vector_type(8))) short bf16x8;
typedef __attribute__((ext_vector_type(4))) float f32x4;
typedef __attribute__((ext_vector_type(4))) unsigned int uint4v;
typedef unsigned short ushort_t;
typedef unsigned long long u64_t;

__device__ __forceinline__ ushort_t f2bf(float f) {
    __hip_bfloat16 h = __float2bfloat16(f);   // RNE rounding
    return *reinterpret_cast<ushort_t*>(&h);
}
__device__ __forceinline__ float sigmoid_f(float x) { return 1.f / (1.f + __expf(-x)); }
__device__ __forceinline__ float tanh_f(float x) { return 1.f - 2.f / (__expf(2.f * x) + 1.f); }

__device__ __forceinline__ void lds_barrier() {
    asm volatile("s_waitcnt lgkmcnt(0)\n\ts_barrier" ::: "memory");
}

// R20: producer/consumer WAVE SPECIALIZATION.
//  * R18 proved a phase costs 4.3us even with h L2-resident for 13us -> not
//    producer-wait. R19 proved `nt` bypasses L2 (FETCH +16MB) -> dead end.
//    Root cause (explains ALL protocol-invariance): vmcnt retires IN ISSUE
//    ORDER, and every wave's stream has its own previous sc0 sc1 h-store
//    (write-through -> HBM-bound ack, us-scale) AHEAD of the probe loads, so
//    every probe vmcnt(0) transitively waits the store ack. R15 (pred-RMW
//    removal) was neutral because the H-store remained. This is the 4.3us.
//  * Fix: waves 0-3 = consumers — probe h (16 entries/thread), stage ALL of
//    hS, load x for 2 row-slots each. Their vm streams contain ONLY fast
//    loads -> probe vmcnt(0) = one L2 RT. Waves 4-7 = storers — read packed
//    h from LDS hOutS, fire sc0 sc1 stores (2 entries/one dwordx4), NEVER
//    vmcnt-wait (vmcnt(40) cap retires only multi-step-old acks = free).
//  * All waves still do E (gate GEMMs, unchanged (gate,half)=w chunks) and
//    G (c-update for their fixed (urow,upair); hv -> hOutS).
//  * Protocol R12-verbatim: u64 {tag|2xbf16}, sc0 probe round-0, agent/L3
//    escalate (terminating: stores write through to L3), 2-slot hbuf
//    (causality: stores at G(t) happen after this block's C(t) staging read;
//    cross-block induction unchanged). pred via predS LDS (R15-proven).
//  * 3 barriers/step: D (hS+xS visible), F (gact), G2 (hOutS -> storers;
//    storer reads complete before D(t+1), so G(t+1) overwrite is safe).
__global__ __launch_bounds__(512) void lstm_rec(
    const float* __restrict__ X,
    const float* __restrict__ Wf, const float* __restrict__ Wi,
    const float* __restrict__ Wo, const float* __restrict__ Wc,
    const float* __restrict__ bfp, const float* __restrict__ bip,
    const float* __restrict__ bop, const float* __restrict__ bcp,
    const float* __restrict__ Uf, const float* __restrict__ Ui,
    const float* __restrict__ Uo, const float* __restrict__ Uc,
    const float* __restrict__ Wfc,
    float* __restrict__ pred, u64_t* __restrict__ hbuf,
    unsigned int* __restrict__ xcdtab,
    float* __restrict__ outH, float* __restrict__ outC)
{
    __shared__ ushort_t hS[16 * 520];
    __shared__ ushort_t xS[16 * 264];
    __shared__ float gact[4][16][68];
    __shared__ unsigned int hOutS[16][32];
    __shared__ float predS[16][512];
    __shared__ int meta[2];   // [0]=rank, [1]=uniform

    const int tid  = threadIdx.x;
    const int w    = tid >> 6;
    const int lane = tid & 63;
    const int q    = lane >> 4;
    const int m    = lane & 15;
    const int gate = w >> 1;
    const int half = w & 1;

    // ---- XCD self-assignment: wave 0 computes, LDS-broadcasts (R9-proven) ----
    if (w == 0) {
        unsigned int xcd;
        asm volatile("s_getreg_b32 %0, hwreg(HW_REG_XCC_ID)" : "=s"(xcd));
        xcd &= 15u;
        if (lane == 0)
            __hip_atomic_store(&xcdtab[blockIdx.x], xcd + 1u,
                               __ATOMIC_RELEASE, __HIP_MEMORY_SCOPE_AGENT);
        unsigned int entry;
        for (;;) {
            entry = __hip_atomic_load(&xcdtab[lane], __ATOMIC_ACQUIRE, __HIP_MEMORY_SCOPE_AGENT);
            if (__ballot(entry != 0u) == ~0ull) break;
            __builtin_amdgcn_s_sleep(1);
        }
        const unsigned int xcd_j = entry - 1u;
        const unsigned int key_j = (xcd_j << 8) | (unsigned int)lane;
        const unsigned int mykey = (xcd << 8) | (unsigned int)blockIdx.x;
        const int rank = __popcll(__ballot(key_j < mykey));
        const int c_lt = __popcll(__ballot(xcd_j < xcd));
        const int c_eq = __popcll(__ballot(xcd_j == xcd));
        const int gg   = rank >> 3;
        const bool uni = (c_lt <= gg * 8) && (gg * 8 + 8 <= c_lt + c_eq);
        if (lane == 0) { meta[0] = rank; meta[1] = uni ? 1 : 0; }
    }
    __syncthreads();
    const int  rank    = meta[0];
    const bool uniform = meta[1] != 0;
    if (rank >= 32) return;
    const int g = rank >> 3;
    const int s = rank & 7;

    const bool cons = (tid < 256);   // waves 0-3 consumers; 4-7 storers

    const int ncol0 = s * 64 + half * 32 + m;
    const int ncol1 = ncol0 + 16;

    const float* Ug = (gate == 0) ? Uf : (gate == 1) ? Ui : (gate == 2) ? Uo : Uc;
    const float* Wg = (gate == 0) ? Wf : (gate == 1) ? Wi : (gate == 2) ? Wo : Wc;
    const float* bg = (gate == 0) ? bfp : (gate == 1) ? bip : (gate == 2) ? bop : bcp;

    const float bias0 = bg[ncol0];
    const float bias1 = bg[ncol1];

    // ---- one-time: B-fragments into registers (fp32 -> bf16 RNE) ----
    bf16x8 UF[2][16];
    bf16x8 WF[2][8];
    #pragma unroll
    for (int tt = 0; tt < 2; ++tt) {
        const int nc = tt ? ncol1 : ncol0;
        #pragma unroll
        for (int ks = 0; ks < 16; ++ks) {
            bf16x8 v;
            #pragma unroll
            for (int j = 0; j < 8; ++j)
                v[j] = (short)f2bf(Ug[(ks * 32 + q * 8 + j) * H_ + nc]);
            UF[tt][ks] = v;
        }
        #pragma unroll
        for (int ks = 0; ks < 8; ++ks) {
            bf16x8 v;
            #pragma unroll
            for (int j = 0; j < 8; ++j)
                v[j] = (short)f2bf(Wg[(ks * 32 + q * 8 + j) * H_ + nc]);
            WF[tt][ks] = v;
        }
    }

    const int urow  = tid >> 5;
    const int upair = tid & 31;
    const float2 wfc2 = *(const float2*)&Wfc[s * 64 + 2 * upair];

    float cr0 = 0.f, cr1 = 0.f;

    // consumer geometry: 16 hbuf entries (128B) per thread; 2 x-row-slots
    const int crow   = tid >> 4;          // 0..15 (consumers only)
    const int cchunk = tid & 15;          // 16 u64 entries each
    u64_t* peA = hbuf + ((size_t)(0 * B_ + g * 16 + crow) * 256 + cchunk * 16);
    u64_t* peB = hbuf + ((size_t)(1 * B_ + g * 16 + crow) * 256 + cchunk * 16);
    const int xs0 = tid * 2, xs1 = tid * 2 + 1;          // x slots (consumers)
    const int xrow0 = xs0 >> 5, xup0 = xs0 & 31;
    const int xrow1 = xs1 >> 5, xup1 = xs1 & 31;

    // ---- preamble: zero predS; consumers stage x(0) for their 2 slots ----
    #pragma unroll
    for (int i = 0; i < 16; ++i)
        predS[(tid * 16 + i) >> 9][(tid * 16 + i) & 511] = 0.f;
    if (cons) {
        const float* xa = &X[((size_t)(g * 16 + xrow0) * S_ + 0) * D_ + xup0 * 8];
        const float* xb = &X[((size_t)(g * 16 + xrow1) * S_ + 0) * D_ + xup1 * 8];
        float4 a0 = *(const float4*)xa, a1 = *(const float4*)(xa + 4);
        float4 b0 = *(const float4*)xb, b1 = *(const float4*)(xb + 4);
        bf16x8 v;
        v[0] = (short)f2bf(a0.x); v[1] = (short)f2bf(a0.y);
        v[2] = (short)f2bf(a0.z); v[3] = (short)f2bf(a0.w);
        v[4] = (short)f2bf(a1.x); v[5] = (short)f2bf(a1.y);
        v[6] = (short)f2bf(a1.z); v[7] = (short)f2bf(a1.w);
        *(bf16x8*)&xS[xrow0 * 264 + xup0 * 8] = v;
        v[0] = (short)f2bf(b0.x); v[1] = (short)f2bf(b0.y);
        v[2] = (short)f2bf(b0.z); v[3] = (short)f2bf(b0.w);
        v[4] = (short)f2bf(b1.x); v[5] = (short)f2bf(b1.y);
        v[6] = (short)f2bf(b1.z); v[7] = (short)f2bf(b1.w);
        *(bf16x8*)&xS[xrow1 * 264 + xup1 * 8] = v;
    }

    float4 xr00, xr01, xr10, xr11;

    for (int t = 0; t < S_; ++t) {
        // ---- C (consumers only): probe+stage h(t); clean vm stream ----
        if (cons) {
            u64_t* pe = (t & 1) ? peB : peA;
            const unsigned int tg = (unsigned int)t;
            uint4v ra0, ra1, ra2, ra3;         // lo dwords, 16 entries
            bool got = false;
            if (uniform) {
                uint4v r0, r1, r2, r3, r4, r5, r6, r7;
                asm volatile(
                    "global_load_dwordx4 %0, %4, off sc0\n\t"
                    "global_load_dwordx4 %1, %5, off sc0\n\t"
                    "global_load_dwordx4 %2, %6, off sc0\n\t"
                    "global_load_dwordx4 %3, %7, off sc0"
                    : "=v"(r0), "=v"(r1), "=v"(r2), "=v"(r3)
                    : "v"(pe), "v"(pe + 2), "v"(pe + 4), "v"(pe + 6)
                    : "memory");
                asm volatile(
                    "global_load_dwordx4 %0, %4, off sc0\n\t"
                    "global_load_dwordx4 %1, %5, off sc0\n\t"
                    "global_load_dwordx4 %2, %6, off sc0\n\t"
                    "global_load_dwordx4 %3, %7, off sc0\n\t"
                    "s_waitcnt vmcnt(0)"
                    : "=v"(r4), "=v"(r5), "=v"(r6), "=v"(r7)
                    : "v"(pe + 8), "v"(pe + 10), "v"(pe + 12), "v"(pe + 14)
                    : "memory");
                bool ok = r0[1] == tg && r0[3] == tg && r1[1] == tg && r1[3] == tg
                       && r2[1] == tg && r2[3] == tg && r3[1] == tg && r3[3] == tg
                       && r4[1] == tg && r4[3] == tg && r5[1] == tg && r5[3] == tg
                       && r6[1] == tg && r6[3] == tg && r7[1] == tg && r7[3] == tg;
                if (__ballot(ok) == ~0ull) {
                    ra0[0] = r0[0]; ra0[1] = r0[2]; ra0[2] = r1[0]; ra0[3] = r1[2];
                    ra1[0] = r2[0]; ra1[1] = r2[2]; ra1[2] = r3[0]; ra1[3] = r3[2];
                    ra2[0] = r4[0]; ra2[1] = r4[2]; ra2[2] = r5[0]; ra2[3] = r5[2];
                    ra3[0] = r6[0]; ra3[1] = r6[2]; ra3[2] = r7[0]; ra3[3] = r7[2];
                    got = true;
                }
            }
            if (!got) {
                // escalation: agent-atomic u64 loads (L3-fresh; data+tag travel
                // together -> no stale-spin). R12-proven, terminating.
                for (;;) {
                    u64_t ev[16];
                    #pragma unroll
                    for (int e = 0; e < 16; ++e)
                        ev[e] = __hip_atomic_load(pe + e, __ATOMIC_RELAXED,
                                                  __HIP_MEMORY_SCOPE_AGENT);
                    bool ok = true;
                    #pragma unroll
                    for (int e = 0; e < 16; ++e)
                        ok = ok && ((unsigned int)(ev[e] >> 32) == tg);
                    if (__ballot(ok) == ~0ull) {
                        ra0[0] = (unsigned int)ev[0];  ra0[1] = (unsigned int)ev[1];
                        ra0[2] = (unsigned int)ev[2];  ra0[3] = (unsigned int)ev[3];
                        ra1[0] = (unsigned int)ev[4];  ra1[1] = (unsigned int)ev[5];
                        ra1[2] = (unsigned int)ev[6];  ra1[3] = (unsigned int)ev[7];
                        ra2[0] = (unsigned int)ev[8];  ra2[1] = (unsigned int)ev[9];
                        ra2[2] = (unsigned int)ev[10]; ra2[3] = (unsigned int)ev[11];
                        ra3[0] = (unsigned int)ev[12]; ra3[1] = (unsigned int)ev[13];
                        ra3[2] = (unsigned int)ev[14]; ra3[3] = (unsigned int)ev[15];
                        break;
                    }
                    __builtin_amdgcn_s_sleep(1);
                }
            }
            // x(t+1) prefetch for both slots (consumed in G this step)
            if (t + 1 < S_) {
                const float* xa = &X[((size_t)(g * 16 + xrow0) * S_ + (t + 1)) * D_ + xup0 * 8];
                const float* xb = &X[((size_t)(g * 16 + xrow1) * S_ + (t + 1)) * D_ + xup1 * 8];
                xr00 = *(const float4*)xa; xr01 = *(const float4*)(xa + 4);
                xr10 = *(const float4*)xb; xr11 = *(const float4*)(xb + 4);
            }
            // stage to hS: 16 entries = 32 ushort-pairs at crow,cchunk
            ushort_t* hb = &hS[crow * 520 + cchunk * 32];
            *(uint4v*)(hb)      = ra0;
            *(uint4v*)(hb + 8)  = ra1;
            *(uint4v*)(hb + 16) = ra2;
            *(uint4v*)(hb + 24) = ra3;
        }
        lds_barrier();   // D: hS (+ xS from G(t-1)) visible

        // ---- E: gate GEMMs + activations (all waves) ----
        f32x4 accA0 = {bias0, bias0, bias0, bias0};
        f32x4 accA1 = {bias1, bias1, bias1, bias1};
        f32x4 accB0 = {0.f, 0.f, 0.f, 0.f};
        f32x4 accB1 = {0.f, 0.f, 0.f, 0.f};
        #pragma unroll
        for (int ks = 0; ks < 8; ++ks) {
            bf16x8 a = *(const bf16x8*)&xS[m * 264 + ks * 32 + q * 8];
            accA0 = __builtin_amdgcn_mfma_f32_16x16x32_bf16(a, WF[0][ks], accA0, 0, 0, 0);
            accA1 = __builtin_amdgcn_mfma_f32_16x16x32_bf16(a, WF[1][ks], accA1, 0, 0, 0);
        }
        #pragma unroll
        for (int ks = 0; ks < 16; ++ks) {
            bf16x8 a = *(const bf16x8*)&hS[m * 520 + ks * 32 + q * 8];
            accB0 = __builtin_amdgcn_mfma_f32_16x16x32_bf16(a, UF[0][ks], accB0, 0, 0, 0);
            accB1 = __builtin_amdgcn_mfma_f32_16x16x32_bf16(a, UF[1][ks], accB1, 0, 0, 0);
        }
        #pragma unroll
        for (int j = 0; j < 4; ++j) {
            float v0 = accA0[j] + accB0[j];
            float v1 = accA1[j] + accB1[j];
            v0 = (gate < 3) ? sigmoid_f(v0) : tanh_f(v0);
            v1 = (gate < 3) ? sigmoid_f(v1) : tanh_f(v1);
            gact[gate][q * 4 + j][half * 32 + m]      = v0;
            gact[gate][q * 4 + j][half * 32 + 16 + m] = v1;
        }
        lds_barrier();   // F: gact visible

        // ---- G: c-update (all waves); hv -> hOutS; consumers write xS(t+1) ----
        float2 f2v = *(const float2*)&gact[0][urow][2 * upair];
        float2 i2v = *(const float2*)&gact[1][urow][2 * upair];
        float2 o2v = *(const float2*)&gact[2][urow][2 * upair];
        float2 ch2 = *(const float2*)&gact[3][urow][2 * upair];
        cr0 = f2v.x * cr0 + i2v.x * ch2.x;
        cr1 = f2v.y * cr1 + i2v.y * ch2.y;
        float hv0 = o2v.x * tanh_f(cr0);
        float hv1 = o2v.y * tanh_f(cr1);

        hOutS[urow][upair] = (unsigned int)f2bf(hv0) | ((unsigned int)f2bf(hv1) << 16);

        if (cons && t + 1 < S_) {
            bf16x8 v;
            v[0] = (short)f2bf(xr00.x); v[1] = (short)f2bf(xr00.y);
            v[2] = (short)f2bf(xr00.z); v[3] = (short)f2bf(xr00.w);
            v[4] = (short)f2bf(xr01.x); v[5] = (short)f2bf(xr01.y);
            v[6] = (short)f2bf(xr01.z); v[7] = (short)f2bf(xr01.w);
            *(bf16x8*)&xS[xrow0 * 264 + xup0 * 8] = v;
            v[0] = (short)f2bf(xr10.x); v[1] = (short)f2bf(xr10.y);
            v[2] = (short)f2bf(xr10.z); v[3] = (short)f2bf(xr10.w);
            v[4] = (short)f2bf(xr11.x); v[5] = (short)f2bf(xr11.y);
            v[6] = (short)f2bf(xr11.z); v[7] = (short)f2bf(xr11.w);
            *(bf16x8*)&xS[xrow1 * 264 + xup1 * 8] = v;
        }

        if (t == S_ - 1) {
            *(float2*)&outH[(g * 16 + urow) * H_ + s * 64 + 2 * upair] = make_float2(hv0, hv1);
            *(float2*)&outC[(g * 16 + urow) * H_ + s * 64 + 2 * upair] = make_float2(cr0, cr1);
        }

        // ---- pred head: LDS partial (no global RMW in the loop; R15) ----
        float pv = hv0 * wfc2.x + hv1 * wfc2.y;
        pv += __shfl_xor(pv, 16);
        pv += __shfl_xor(pv, 8);
        pv += __shfl_xor(pv, 4);
        pv += __shfl_xor(pv, 2);
        pv += __shfl_xor(pv, 1);
        if (upair == 0) predS[urow][t] = pv;

        lds_barrier();   // G2: hOutS visible to storers

        // ---- storers: fire h(t+1) entries; NEVER vmcnt-wait on them.
        //      Their hOutS reads finish before D(t+1), so G(t+1) is safe. ----
        if (!cons && t + 1 < S_) {
            asm volatile("s_waitcnt vmcnt(40)" ::: "memory");  // cap: retires only
                                                               // multi-step-old acks
            const unsigned int tv = (unsigned int)(t + 1);
            const int eidx = (tid - 256) * 2;       // 2 entries, same row
            const int erow = eidx >> 5;
            const int eup  = eidx & 31;
            unsigned int d0 = hOutS[erow][eup];
            unsigned int d1 = hOutS[erow][eup + 1];
            uint4v st;
            st[0] = d0; st[1] = tv; st[2] = d1; st[3] = tv;
            u64_t* hdst = hbuf + ((size_t)(((t + 1) & 1) * B_ + g * 16 + erow) * 256
                                  + s * 32 + eup);
            asm volatile("global_store_dwordx4 %0, %1, off sc0 sc1"
                         :: "v"(hdst), "v"(st) : "memory");
        }
    }

    // ---- one-time pred flush: cross-slice sum via atomicAdd (off recurrence) ----
    lds_barrier();
    #pragma unroll
    for (int i = 0; i < 16; ++i) {
        const int idx = tid * 16 + i;
        const int row = idx >> 9;
        const int tt  = idx & 511;
        atomicAdd(&pred[(g * 16 + row) * S_ + tt], predS[row][tt]);
    }
}

__global__ void pred_fin(const float* __restrict__ pred,
                         const float* __restrict__ bfc,
                         float* __restrict__ out)
{
    int i = blockIdx.x * blockDim.x + threadIdx.x;
    if (i < B_ * S_) out[i] = pred[i] + bfc[0];
}

extern "C" void kernel_launch(void* const* d_in, const int* in_sizes, int n_in,
                              void* d_out, int out_size, void* d_ws, size_t ws_size,
                              hipStream_t stream) {
    const float* X   = (const float*)d_in[0];
    const float* Wf  = (const float*)d_in[1];
    const float* Wi  = (const float*)d_in[2];
    const float* Wo  = (const float*)d_in[3];
    const float* Wc  = (const float*)d_in[4];
    const float* bfp = (const float*)d_in[5];
    const float* bip = (const float*)d_in[6];
    const float* bop = (const float*)d_in[7];
    const float* bcp = (const float*)d_in[8];
    const float* Uf  = (const float*)d_in[9];
    const float* Ui  = (const float*)d_in[10];
    const float* Uo  = (const float*)d_in[11];
    const float* Uc  = (const float*)d_in[12];
    const float* Wfc = (const float*)d_in[13];
    const float* bfc = (const float*)d_in[14];

    // ws layout: pred fp32 [64][512] @0 (131072 B)
    //            | hbuf u64 [2][64][256] @131072 (262144 B)
    //            | xcdtab @393216 (256 B)
    float*        pred   = (float*)d_ws;
    u64_t*        hbuf   = (u64_t*)((char*)d_ws + 131072);
    unsigned int* xcdtab = (unsigned int*)((char*)d_ws + 393216);

    hipMemsetAsync(d_ws, 0, 393472, stream);   // pred, hbuf (tags=0), xcdtab

    float* out = (float*)d_out;
    lstm_rec<<<64, 512, 0, stream>>>(X, Wf, Wi, Wo, Wc, bfp, bip, bop, bcp,
                                     Uf, Ui, Uo, Uc, Wfc,
                                     pred, hbuf, xcdtab,
                                     out + 32768, out + 65536);
    pred_fin<<<128, 256, 0, stream>>>(pred, bfc, out);
}